// Round 9
// baseline (198.375 us; speedup 1.0000x reference)
//
#include <hip/hip_runtime.h>
#include <hip/hip_bf16.h>

#define DEV __device__ __forceinline__

typedef __bf16 bf16x8 __attribute__((ext_vector_type(8)));
typedef float f32x4 __attribute__((ext_vector_type(4)));
typedef float f32x16 __attribute__((ext_vector_type(16)));
using u16 = unsigned short;
using u32 = unsigned int;

static constexpr int S = 2048;
static constexpr int D = 1024;
static constexpr float SCQ = 0.125f * 1.44269504088896340736f;  // 1/sqrt(64)*log2(e)

DEV u16 f2bf(float f) {  // RNE
  unsigned u = __builtin_bit_cast(unsigned, f);
  u += 0x7fffu + ((u >> 16) & 1u);
  return (u16)(u >> 16);
}
DEV u16 f2bfr(float f) {  // round-half-up (cheap)
  return (u16)((__builtin_bit_cast(u32, f) + 0x8000u) >> 16);
}
// two f32 -> packed bf16x2, round-half-up: 2 int adds + one v_perm
DEV u32 pk2(float a, float b) {
  u32 ua = __builtin_bit_cast(u32, a) + 0x8000u;
  u32 ub = __builtin_bit_cast(u32, b) + 0x8000u;
  return __builtin_amdgcn_perm(ub, ua, 0x07060302);  // {lo: a, hi: b}
}

// async global->LDS DMA, 16B per lane. LDS dest is wave-uniform base + lane*16
// (dest must be linear in lane order; global src is per-lane).
DEV void gl16(const u16* __restrict__ g, u16* l) {
  __builtin_amdgcn_global_load_lds((const __attribute__((address_space(1))) u32*)g,
                                   (__attribute__((address_space(3))) u32*)l, 16, 0, 0);
}

// ---- merged prep: x pack + W_qkv transpose + W_out transpose (one dispatch) ----
__global__ __launch_bounds__(256) void k_prep(const float* __restrict__ x, u16* __restrict__ Xb,
                                              const float* __restrict__ Wqkv, u16* __restrict__ WqkvT,
                                              const float* __restrict__ Wout, u16* __restrict__ WoutT) {
  __shared__ float t[32][33];
  const int bid = blockIdx.x;
  const int tid = threadIdx.x;
  if (bid < 4096) {  // pack x: 4096 blocks x 256 threads x 1 float4
    const int i = bid * 256 + tid;
    const float4 v = reinterpret_cast<const float4*>(x)[i];
    ushort4 o;
    o.x = f2bf(v.x); o.y = f2bf(v.y); o.z = f2bf(v.z); o.w = f2bf(v.w);
    reinterpret_cast<ushort4*>(Xb)[i] = o;
    return;
  }
  const float* in;
  u16* out;
  int R, C, bx, by;
  if (bid < 4096 + 3072) {  // W_qkv [1024][3072] -> [3072][1024]
    const int b = bid - 4096;
    in = Wqkv; out = WqkvT; R = 1024; C = 3072;
    bx = b % 96; by = b / 96;
  } else {  // W_out [1024][1024] -> [1024][1024]^T
    const int b = bid - 7168;
    in = Wout; out = WoutT; R = 1024; C = 1024;
    bx = b & 31; by = b >> 5;
  }
  const int tx = tid & 31, ty = tid >> 5;
  const int c0 = bx * 32, r0 = by * 32;
  for (int i = ty; i < 32; i += 8)
    t[i][tx] = in[(size_t)(r0 + i) * C + c0 + tx];
  __syncthreads();
  for (int i = ty; i < 32; i += 8)
    out[(size_t)(c0 + i) * R + r0 + tx] = f2bf(t[tx][i]);
}

// ---- 128x128 bf16 GEMM (QKV): dbuf gl_lds pipeline + LT overlay + XCD swizzle ----
__global__ __launch_bounds__(256, 5) void k_gemm0(const u16* __restrict__ A, const u16* __restrict__ Bt,
                                                  const float* __restrict__ bias, int M, int N, int K,
                                                  u16* __restrict__ Qb, u16* __restrict__ Kb,
                                                  u16* __restrict__ Vt) {
  constexpr int TN = 128, NJ = 4;
  constexpr int ASZ = 2 * 128 * 32 * 2;  // 16384
  __shared__ __align__(16) char smem[ASZ + 2 * TN * 32 * 2];  // 32768
  auto As = reinterpret_cast<u16(*)[128][32]>(smem);
  auto Bs = reinterpret_cast<u16(*)[TN][32]>(smem + ASZ);
  auto LT = reinterpret_cast<u16(*)[136]>(smem);  // epilogue-only overlay, 64x136x2 = 17408B
  const int tid = threadIdx.x;
  const int lane = tid & 63, wave = tid >> 6;
  const int l15 = lane & 15, quad = lane >> 4;
  // XCD swizzle: nwg = 24*32 = 768, chunk = 96 (4 M-rows of 24)
  const int bid0 = blockIdx.x + 24 * blockIdx.y;
  const int bid = (bid0 & 7) * 96 + (bid0 >> 3);
  const int m0 = (bid / 24) * 128, n0 = (bid % 24) * TN;
  const int wm = (wave >> 1) * 64, wn = (wave & 1) * (TN / 2);
  const int lr = lane >> 2;  // 0..15: row within a 16-row staging group
  const int lcs = ((((lane & 3) - (lane >> 3)) & 3)) * 8;   // inverse-swizzled source col
  const int sq = ((quad + (l15 >> 1)) & 3) * 8;             // swizzled read col

  f32x4 acc[4][NJ];
#pragma unroll
  for (int i = 0; i < 4; i++)
#pragma unroll
    for (int j = 0; j < NJ; j++) acc[i][j] = (f32x4){0.f, 0.f, 0.f, 0.f};

  const u16* Aw0 = &A[(size_t)(m0 + wave * 32 + lr) * K + lcs];
  const u16* Aw1 = &A[(size_t)(m0 + wave * 32 + 16 + lr) * K + lcs];
  const u16* Bw0 = &Bt[(size_t)(n0 + wave * 32 + lr) * K + lcs];
  const u16* Bw1 = &Bt[(size_t)(n0 + wave * 32 + 16 + lr) * K + lcs];

  gl16(Aw0, &As[0][wave * 32][0]);
  gl16(Aw1, &As[0][wave * 32 + 16][0]);
  gl16(Bw0, &Bs[0][wave * 32][0]);
  gl16(Bw1, &Bs[0][wave * 32 + 16][0]);

  int cur = 0;
#pragma unroll 2
  for (int kk = 0; kk < K; kk += 32, cur ^= 1) {
    __syncthreads();
    if (kk + 32 < K) {
      gl16(Aw0 + kk + 32, &As[cur ^ 1][wave * 32][0]);
      gl16(Aw1 + kk + 32, &As[cur ^ 1][wave * 32 + 16][0]);
      gl16(Bw0 + kk + 32, &Bs[cur ^ 1][wave * 32][0]);
      gl16(Bw1 + kk + 32, &Bs[cur ^ 1][wave * 32 + 16][0]);
    }
    bf16x8 af[4], bfv[NJ];
#pragma unroll
    for (int i = 0; i < 4; i++)
      af[i] = *reinterpret_cast<const bf16x8*>(&As[cur][wm + i * 16 + l15][sq]);
#pragma unroll
    for (int j = 0; j < NJ; j++)
      bfv[j] = *reinterpret_cast<const bf16x8*>(&Bs[cur][wn + j * 16 + l15][sq]);
#pragma unroll
    for (int i = 0; i < 4; i++)
#pragma unroll
      for (int j = 0; j < NJ; j++)
        acc[i][j] = __builtin_amdgcn_mfma_f32_16x16x32_bf16(af[i], bfv[j], acc[i][j], 0, 0, 0);
  }

  if (n0 >= 2048) {
    // ---- V blocks: LDS transpose (LT overlays As/Bs) -> coalesced stores along s ----
    const int b = m0 >> 11, sbase = m0 & 2047;
#pragma unroll
    for (int p = 0; p < 2; p++) {
      __syncthreads();
      if ((wave & 1) == p) {
#pragma unroll
        for (int j = 0; j < NJ; j++) {
          const int n = n0 + wn + j * 16 + l15;
          const float vb = bias[n];
#pragma unroll
          for (int i = 0; i < 4; i++) {
            uint2 pw;
            pw.x = pk2(acc[i][j][0] + vb, acc[i][j][1] + vb);
            pw.y = pk2(acc[i][j][2] + vb, acc[i][j][3] + vb);
            *reinterpret_cast<uint2*>(&LT[j * 16 + l15][wm + i * 16 + quad * 4]) = pw;
          }
        }
      }
      __syncthreads();
      const int h = ((n0 - 2048) >> 6) + p;
      const int bh = b * 16 + h;
      const int nl = tid >> 2, cc = (tid & 3) * 32;
      u16* dst = &Vt[((size_t)bh * 64 + nl) * S + sbase + cc];
#pragma unroll
      for (int k = 0; k < 4; k++)
        reinterpret_cast<uint4*>(dst)[k] = *reinterpret_cast<const uint4*>(&LT[nl][cc + k * 8]);
    }
  } else {
    // ---- Q/K blocks: direct stores (coalesced over l15) ----
#pragma unroll
    for (int i = 0; i < 4; i++) {
#pragma unroll
      for (int j = 0; j < NJ; j++) {
#pragma unroll
        for (int r = 0; r < 4; r++) {
          const int m = m0 + wm + i * 16 + quad * 4 + r;
          const int n = n0 + wn + j * 16 + l15;
          const float v = acc[i][j][r] + bias[n];
          const int h = (n >> 6) & 15, dh = n & 63;
          const int b = m >> 11, s = m & 2047;
          const int bh = b * 16 + h;
          if (n < 1024) Qb[((size_t)bh * S + s) * 64 + dh] = f2bfr(v * SCQ);
          else          Kb[((size_t)bh * S + s) * 64 + dh] = f2bfr(v);
        }
      }
    }
  }
}

// ---- out-proj GEMM: split-K 128x128 tiles. N=1024 allows only 8 n-tiles, so
// K-split x2 (K=512 each) restores grid to 512 blocks (2/CU) at the 128x128
// MFMA:ds_read ratio (2:1 vs 64x64's 1:1 -> that tile was LDS-read-starved).
// Partials (2x16MB f32) land in post-attn dead workspace; k_red sums + bias.
__global__ __launch_bounds__(256, 5) void k_gemm2(const u16* __restrict__ A, const u16* __restrict__ Bt,
                                                  float* __restrict__ Pp) {
  constexpr int K = 1024, N = 1024, KH = 512;
  constexpr int ASZ = 2 * 128 * 32 * 2;
  __shared__ __align__(16) char smem[2 * ASZ];  // 32768
  auto As = reinterpret_cast<u16(*)[128][32]>(smem);
  auto Bs = reinterpret_cast<u16(*)[128][32]>(smem + ASZ);
  const int tid = threadIdx.x;
  const int lane = tid & 63, wave = tid >> 6;
  const int l15 = lane & 15, quad = lane >> 4;
  // XCD swizzle: nwg = 512, chunk = 64
  const int bid0 = blockIdx.x;
  const int bid = (bid0 & 7) * 64 + (bid0 >> 3);
  const int ks = bid >> 8, rem = bid & 255;
  const int m0 = (rem >> 3) * 128, n0 = (rem & 7) * 128;
  const int koff = ks * KH;
  const int wm = (wave >> 1) * 64, wn = (wave & 1) * 64;
  const int lr = lane >> 2;
  const int lcs = ((((lane & 3) - (lane >> 3)) & 3)) * 8;
  const int sq = ((quad + (l15 >> 1)) & 3) * 8;

  f32x4 acc[4][4];
#pragma unroll
  for (int i = 0; i < 4; i++)
#pragma unroll
    for (int j = 0; j < 4; j++) acc[i][j] = (f32x4){0.f, 0.f, 0.f, 0.f};

  const u16* Aw0 = &A[(size_t)(m0 + wave * 32 + lr) * K + koff + lcs];
  const u16* Aw1 = &A[(size_t)(m0 + wave * 32 + 16 + lr) * K + koff + lcs];
  const u16* Bw0 = &Bt[(size_t)(n0 + wave * 32 + lr) * K + koff + lcs];
  const u16* Bw1 = &Bt[(size_t)(n0 + wave * 32 + 16 + lr) * K + koff + lcs];

  gl16(Aw0, &As[0][wave * 32][0]);
  gl16(Aw1, &As[0][wave * 32 + 16][0]);
  gl16(Bw0, &Bs[0][wave * 32][0]);
  gl16(Bw1, &Bs[0][wave * 32 + 16][0]);

  int cur = 0;
#pragma unroll 2
  for (int kk = 0; kk < KH; kk += 32, cur ^= 1) {
    __syncthreads();
    if (kk + 32 < KH) {
      gl16(Aw0 + kk + 32, &As[cur ^ 1][wave * 32][0]);
      gl16(Aw1 + kk + 32, &As[cur ^ 1][wave * 32 + 16][0]);
      gl16(Bw0 + kk + 32, &Bs[cur ^ 1][wave * 32][0]);
      gl16(Bw1 + kk + 32, &Bs[cur ^ 1][wave * 32 + 16][0]);
    }
    bf16x8 af[4], bfv[4];
#pragma unroll
    for (int i = 0; i < 4; i++)
      af[i] = *reinterpret_cast<const bf16x8*>(&As[cur][wm + i * 16 + l15][sq]);
#pragma unroll
    for (int j = 0; j < 4; j++)
      bfv[j] = *reinterpret_cast<const bf16x8*>(&Bs[cur][wn + j * 16 + l15][sq]);
#pragma unroll
    for (int i = 0; i < 4; i++)
#pragma unroll
      for (int j = 0; j < 4; j++)
        acc[i][j] = __builtin_amdgcn_mfma_f32_16x16x32_bf16(af[i], bfv[j], acc[i][j], 0, 0, 0);
  }

  float* Pq = Pp + (size_t)ks * 4096 * 1024;
#pragma unroll
  for (int i = 0; i < 4; i++)
#pragma unroll
    for (int j = 0; j < 4; j++)
#pragma unroll
      for (int r = 0; r < 4; r++) {
        const int m = m0 + wm + i * 16 + quad * 4 + r;
        const int n = n0 + wn + j * 16 + l15;
        Pq[(size_t)m * N + n] = acc[i][j][r];
      }
}

// ---- split-K reduce: out = p0 + p1 + bias ----
__global__ __launch_bounds__(256) void k_red(const float* __restrict__ p0, const float* __restrict__ p1,
                                             const float* __restrict__ bias, float* __restrict__ out) {
  const int i = blockIdx.x * 256 + threadIdx.x;
  const float4 a = reinterpret_cast<const float4*>(p0)[i];
  const float4 b = reinterpret_cast<const float4*>(p1)[i];
  const float4 c = reinterpret_cast<const float4*>(bias)[i & 255];  // (4i)&1023 = 4*(i&255)
  float4 o;
  o.x = a.x + b.x + c.x;
  o.y = a.y + b.y + c.y;
  o.z = a.z + b.z + c.z;
  o.w = a.w + b.w + c.w;
  reinterpret_cast<float4*>(out)[i] = o;
}

// ---- flash attention, 32x32x16 MFMA, fixed-max softmax (scores bounded) ----
// block = 128 q (4 waves x 32 q), KVBLK=64. XCD swizzle (FETCH 69.7->12.3MB).
// T5 setprio. T12: P fragments built IN-REGISTER via pk2 + v_permlane32_swap.
// Semantics (gfx950): v_permlane32_swap_b32 vdst, vsrc exchanges vdst lanes
// 32-63 with vsrc lanes 0-31 (vdst 0-31 / vsrc 32-63 unchanged). With
// vdst=w0=pk2(z[s8+0],z[s8+1]), vsrc=w2=pk2(z[s8+4],z[s8+5]):
//   w0: hi=0 own(z0,z1)=keys s16+0,1; hi=1 partner-hi0(z4,z5)=keys s16+8,9
//   w2: hi=0 partner-hi1(z0,z1)=keys s16+4,5; hi=1 own(z4,z5)=keys s16+12,13
// matching B-fragment words W0/W2 (elements 2j at key s16+hi*8+2j). R8 had
// vdst/vsrc REVERSED -> within-tile P permutation -> absmax 2.6e-2. Fixed.
__global__ __launch_bounds__(256, 2) void k_attn(const u16* __restrict__ Qb,
                                                 const u16* __restrict__ Kb,
                                                 const u16* __restrict__ Vt,
                                                 u16* __restrict__ attnB) {
  __shared__ u16 Ks[64][72];     // [key][dh]
  __shared__ u16 Vs[64][72];     // [dh][key_local]
  __shared__ u16 Pl[4][32][72];  // epilogue-only now (O staging)
  const int tid = threadIdx.x;
  const int lane = tid & 63, wave = tid >> 6;
  const int l31 = lane & 31, hi = lane >> 5;
  // XCD swizzle: nwg = 512, chunk = 64 (4 bh of 16 q-blocks per XCD)
  const int bid0 = blockIdx.x + 16 * blockIdx.y;
  const int bid = (bid0 & 7) * 64 + (bid0 >> 3);
  const int bh = bid >> 4;
  const int q0 = (bid & 15) * 128;
  const u16* Qh = Qb + (size_t)bh * S * 64;
  const u16* Kh = Kb + (size_t)bh * S * 64;
  const u16* Vh = Vt + (size_t)bh * 64 * S;
  const int qrow = q0 + wave * 32 + l31;
  bf16x8 qf[4];  // Q (pre-scaled by SCQ) as B-operand: n = lane&31 = q
#pragma unroll
  for (int f = 0; f < 4; f++)
    qf[f] = *reinterpret_cast<const bf16x8*>(&Qh[(size_t)qrow * 64 + f * 16 + hi * 8]);

  const int r0 = tid >> 3, c0 = (tid & 7) * 8;  // staging: 8 lanes x 16B per 128B row

  float li = 0.f;
  f32x16 o0, o1;  // O d-tiles: d = dt*32 + (reg&3)+8*(reg>>2)+4*hi
#pragma unroll
  for (int r = 0; r < 16; r++) { o0[r] = 0.f; o1[r] = 0.f; }

  uint4 pk0 = *reinterpret_cast<const uint4*>(&Kh[(size_t)r0 * 64 + c0]);
  uint4 pk1 = *reinterpret_cast<const uint4*>(&Kh[(size_t)(r0 + 32) * 64 + c0]);
  uint4 pv0 = *reinterpret_cast<const uint4*>(&Vh[(size_t)r0 * S + c0]);
  uint4 pv1 = *reinterpret_cast<const uint4*>(&Vh[(size_t)(r0 + 32) * S + c0]);

  for (int kb = 0; kb < S / 64; kb++) {
    __syncthreads();  // prev tile consumed
    *reinterpret_cast<uint4*>(&Ks[r0][c0]) = pk0;
    *reinterpret_cast<uint4*>(&Ks[r0 + 32][c0]) = pk1;
    *reinterpret_cast<uint4*>(&Vs[r0][c0]) = pv0;
    *reinterpret_cast<uint4*>(&Vs[r0 + 32][c0]) = pv1;
    __syncthreads();  // tile ready
    if (kb + 1 < S / 64) {
      const u16* Kn = Kh + (size_t)(kb + 1) * 64 * 64;
      pk0 = *reinterpret_cast<const uint4*>(&Kn[(size_t)r0 * 64 + c0]);
      pk1 = *reinterpret_cast<const uint4*>(&Kn[(size_t)(r0 + 32) * 64 + c0]);
      pv0 = *reinterpret_cast<const uint4*>(&Vh[(size_t)r0 * S + (kb + 1) * 64 + c0]);
      pv1 = *reinterpret_cast<const uint4*>(&Vh[(size_t)(r0 + 32) * S + (kb + 1) * 64 + c0]);
    }
    // QK^T: 2 key-tiles x 4 k-steps (Q pre-scaled -> z is log2-domain score)
    f32x16 z[2];
    __builtin_amdgcn_s_setprio(1);
#pragma unroll
    for (int kt = 0; kt < 2; kt++) {
#pragma unroll
      for (int r = 0; r < 16; r++) z[kt][r] = 0.f;
#pragma unroll
      for (int f = 0; f < 4; f++) {
        const bf16x8 a = *reinterpret_cast<const bf16x8*>(&Ks[kt * 32 + l31][f * 16 + hi * 8]);
        z[kt] = __builtin_amdgcn_mfma_f32_32x32x16_bf16(a, qf[f], z[kt], 0, 0, 0);
      }
    }
    __builtin_amdgcn_s_setprio(0);
    // p = exp2(z); accumulate denominator (4-way partials)
    float s0 = 0.f, s1 = 0.f, s2 = 0.f, s3 = 0.f;
#pragma unroll
    for (int kt = 0; kt < 2; kt++)
#pragma unroll
      for (int r = 0; r < 16; r++) {
        const float p = __builtin_amdgcn_exp2f(z[kt][r]);
        z[kt][r] = p;
        if ((r & 3) == 0) s0 += p; else if ((r & 3) == 1) s1 += p;
        else if ((r & 3) == 2) s2 += p; else s3 += p;
      }
    li += (s0 + s1) + (s2 + s3);
    // PV: A = V^T rows, B = P built in-register (pk2 + permlane32_swap)
    __builtin_amdgcn_s_setprio(1);
#pragma unroll
    for (int kt = 0; kt < 2; kt++) {
#pragma unroll
      for (int s = 0; s < 2; s++) {
        u32 w0 = pk2(z[kt][s * 8 + 0], z[kt][s * 8 + 1]);
        u32 w2 = pk2(z[kt][s * 8 + 4], z[kt][s * 8 + 5]);
        asm("v_permlane32_swap_b32 %0, %1" : "+v"(w0), "+v"(w2));
        u32 w1 = pk2(z[kt][s * 8 + 2], z[kt][s * 8 + 3]);
        u32 w3 = pk2(z[kt][s * 8 + 6], z[kt][s * 8 + 7]);
        asm("v_permlane32_swap_b32 %0, %1" : "+v"(w1), "+v"(w3));
        uint4 wv;
        wv.x = w0; wv.y = w1; wv.z = w2; wv.w = w3;
        const bf16x8 bp = __builtin_bit_cast(bf16x8, wv);
        const int f = kt * 2 + s;
        const bf16x8 av0 = *reinterpret_cast<const bf16x8*>(&Vs[l31][f * 16 + hi * 8]);
        const bf16x8 av1 = *reinterpret_cast<const bf16x8*>(&Vs[32 + l31][f * 16 + hi * 8]);
        o0 = __builtin_amdgcn_mfma_f32_32x32x16_bf16(av0, bp, o0, 0, 0, 0);
        o1 = __builtin_amdgcn_mfma_f32_32x32x16_bf16(av1, bp, o1, 0, 0, 0);
      }
    }
    __builtin_amdgcn_s_setprio(0);
  }
  li += __shfl_xor(li, 32);
  const float inv = 1.f / li;
  // O -> Pl[q][d] (wave-private), then coalesced store
#pragma unroll
  for (int dt = 0; dt < 2; dt++) {
    const f32x16& od = dt ? o1 : o0;
#pragma unroll
    for (int g = 0; g < 4; g++) {
      uint2 ow;
      ow.x = pk2(od[g * 4 + 0] * inv, od[g * 4 + 1] * inv);
      ow.y = pk2(od[g * 4 + 2] * inv, od[g * 4 + 3] * inv);
      *reinterpret_cast<uint2*>(&Pl[wave][l31][dt * 32 + g * 8 + hi * 4]) = ow;
    }
  }
  const int b = bh >> 4, h = bh & 15;
  const int mbase = b * S + q0 + wave * 32;
  const int qr = lane >> 1, ch = (lane & 1) * 32;
  u16* dst = &attnB[(size_t)(mbase + qr) * D + h * 64 + ch];
#pragma unroll
  for (int c = 0; c < 4; c++)
    reinterpret_cast<uint4*>(dst)[c] = *reinterpret_cast<const uint4*>(&Pl[wave][qr][ch + c * 8]);
}

extern "C" void kernel_launch(void* const* d_in, const int* in_sizes, int n_in,
                              void* d_out, int out_size, void* d_ws, size_t ws_size,
                              hipStream_t stream) {
  const float* x = (const float*)d_in[0];
  const float* Wqkv = (const float*)d_in[1];
  const float* bqkv = (const float*)d_in[2];
  const float* Wout = (const float*)d_in[3];
  const float* bout = (const float*)d_in[4];
  float* out = (float*)d_out;

  // Layout: live-late buffers first; the 38MB tail (Xb..Kb) is dead after attn
  // and is reused for the 32MB split-K partials.
  char* p = (char*)d_ws;
  u16* WoutT = (u16*)p; p += (size_t)1024 * 1024 * 2;     // 2MB  (live thru gemm2)
  u16* attnB = (u16*)p; p += (size_t)4096 * 1024 * 2;     // 8MB  (live thru gemm2)
  u16* Xb = (u16*)p;    p += (size_t)4096 * 1024 * 2;     // 8MB  (dead after gemm0)
  u16* WqkvT = (u16*)p; p += (size_t)3072 * 1024 * 2;     // 6MB  (dead after gemm0)
  u16* Vt = (u16*)p;    p += (size_t)32 * 64 * 2048 * 2;  // 8MB  (dead after attn)
  u16* Qb = (u16*)p;    p += (size_t)32 * 2048 * 64 * 2;  // 8MB  (dead after attn)
  u16* Kb = (u16*)p;    p += (size_t)32 * 2048 * 64 * 2;  // 8MB  (dead after attn)
  float* Pp = (float*)Xb;  // 32MB partials overlay dead region (38MB available)

  k_prep<<<4096 + 3072 + 1024, 256, 0, stream>>>(x, Xb, Wqkv, WqkvT, Wout, WoutT);
  k_gemm0<<<dim3(3072 / 128, 4096 / 128), 256, 0, stream>>>(
      Xb, WqkvT, bqkv, 4096, 3072, 1024, Qb, Kb, Vt);
  k_attn<<<dim3(2048 / 128, 32), 256, 0, stream>>>(Qb, Kb, Vt, attnB);
  k_gemm2<<<512, 256, 0, stream>>>(attnB, WoutT, Pp);
  k_red<<<4096, 256, 0, stream>>>(Pp, Pp + (size_t)4096 * 1024, bout, out);
}

// Round 10
// 187.074 us; speedup vs baseline: 1.0604x; 1.0604x over previous
//
#include <hip/hip_runtime.h>
#include <hip/hip_bf16.h>

#define DEV __device__ __forceinline__

typedef __bf16 bf16x8 __attribute__((ext_vector_type(8)));
typedef float f32x4 __attribute__((ext_vector_type(4)));
typedef float f32x16 __attribute__((ext_vector_type(16)));
using u16 = unsigned short;
using u32 = unsigned int;

static constexpr int S = 2048;
static constexpr int D = 1024;
static constexpr float SCQ = 0.125f * 1.44269504088896340736f;  // 1/sqrt(64)*log2(e)

DEV u16 f2bf(float f) {  // RNE
  unsigned u = __builtin_bit_cast(unsigned, f);
  u += 0x7fffu + ((u >> 16) & 1u);
  return (u16)(u >> 16);
}
DEV u16 f2bfr(float f) {  // round-half-up (cheap)
  return (u16)((__builtin_bit_cast(u32, f) + 0x8000u) >> 16);
}
// two f32 -> packed bf16x2, round-half-up: 2 int adds + one v_perm
DEV u32 pk2(float a, float b) {
  u32 ua = __builtin_bit_cast(u32, a) + 0x8000u;
  u32 ub = __builtin_bit_cast(u32, b) + 0x8000u;
  return __builtin_amdgcn_perm(ub, ua, 0x07060302);  // {lo: a, hi: b}
}

// async global->LDS DMA, 16B per lane. LDS dest is wave-uniform base + lane*16
// (dest must be linear in lane order; global src is per-lane).
DEV void gl16(const u16* __restrict__ g, u16* l) {
  __builtin_amdgcn_global_load_lds((const __attribute__((address_space(1))) u32*)g,
                                   (__attribute__((address_space(3))) u32*)l, 16, 0, 0);
}

// ---- merged prep: x pack + W_qkv transpose + W_out transpose (one dispatch) ----
__global__ __launch_bounds__(256) void k_prep(const float* __restrict__ x, u16* __restrict__ Xb,
                                              const float* __restrict__ Wqkv, u16* __restrict__ WqkvT,
                                              const float* __restrict__ Wout, u16* __restrict__ WoutT) {
  __shared__ float t[32][33];
  const int bid = blockIdx.x;
  const int tid = threadIdx.x;
  if (bid < 4096) {  // pack x: 4096 blocks x 256 threads x 1 float4
    const int i = bid * 256 + tid;
    const float4 v = reinterpret_cast<const float4*>(x)[i];
    ushort4 o;
    o.x = f2bf(v.x); o.y = f2bf(v.y); o.z = f2bf(v.z); o.w = f2bf(v.w);
    reinterpret_cast<ushort4*>(Xb)[i] = o;
    return;
  }
  const float* in;
  u16* out;
  int R, C, bx, by;
  if (bid < 4096 + 3072) {  // W_qkv [1024][3072] -> [3072][1024]
    const int b = bid - 4096;
    in = Wqkv; out = WqkvT; R = 1024; C = 3072;
    bx = b % 96; by = b / 96;
  } else {  // W_out [1024][1024] -> [1024][1024]^T
    const int b = bid - 7168;
    in = Wout; out = WoutT; R = 1024; C = 1024;
    bx = b & 31; by = b >> 5;
  }
  const int tx = tid & 31, ty = tid >> 5;
  const int c0 = bx * 32, r0 = by * 32;
  for (int i = ty; i < 32; i += 8)
    t[i][tx] = in[(size_t)(r0 + i) * C + c0 + tx];
  __syncthreads();
  for (int i = ty; i < 32; i += 8)
    out[(size_t)(c0 + i) * R + r0 + tx] = f2bf(t[tx][i]);
}

// ---- 128x128 bf16 GEMM (QKV): dbuf gl_lds pipeline + LT overlay + XCD swizzle ----
__global__ __launch_bounds__(256, 5) void k_gemm0(const u16* __restrict__ A, const u16* __restrict__ Bt,
                                                  const float* __restrict__ bias, int M, int N, int K,
                                                  u16* __restrict__ Qb, u16* __restrict__ Kb,
                                                  u16* __restrict__ Vt) {
  constexpr int TN = 128, NJ = 4;
  constexpr int ASZ = 2 * 128 * 32 * 2;  // 16384
  __shared__ __align__(16) char smem[ASZ + 2 * TN * 32 * 2];  // 32768
  auto As = reinterpret_cast<u16(*)[128][32]>(smem);
  auto Bs = reinterpret_cast<u16(*)[TN][32]>(smem + ASZ);
  auto LT = reinterpret_cast<u16(*)[136]>(smem);  // epilogue-only overlay, 64x136x2 = 17408B
  const int tid = threadIdx.x;
  const int lane = tid & 63, wave = tid >> 6;
  const int l15 = lane & 15, quad = lane >> 4;
  // XCD swizzle: nwg = 24*32 = 768, chunk = 96 (4 M-rows of 24)
  const int bid0 = blockIdx.x + 24 * blockIdx.y;
  const int bid = (bid0 & 7) * 96 + (bid0 >> 3);
  const int m0 = (bid / 24) * 128, n0 = (bid % 24) * TN;
  const int wm = (wave >> 1) * 64, wn = (wave & 1) * (TN / 2);
  const int lr = lane >> 2;  // 0..15: row within a 16-row staging group
  const int lcs = ((((lane & 3) - (lane >> 3)) & 3)) * 8;   // inverse-swizzled source col
  const int sq = ((quad + (l15 >> 1)) & 3) * 8;             // swizzled read col

  f32x4 acc[4][NJ];
#pragma unroll
  for (int i = 0; i < 4; i++)
#pragma unroll
    for (int j = 0; j < NJ; j++) acc[i][j] = (f32x4){0.f, 0.f, 0.f, 0.f};

  const u16* Aw0 = &A[(size_t)(m0 + wave * 32 + lr) * K + lcs];
  const u16* Aw1 = &A[(size_t)(m0 + wave * 32 + 16 + lr) * K + lcs];
  const u16* Bw0 = &Bt[(size_t)(n0 + wave * 32 + lr) * K + lcs];
  const u16* Bw1 = &Bt[(size_t)(n0 + wave * 32 + 16 + lr) * K + lcs];

  gl16(Aw0, &As[0][wave * 32][0]);
  gl16(Aw1, &As[0][wave * 32 + 16][0]);
  gl16(Bw0, &Bs[0][wave * 32][0]);
  gl16(Bw1, &Bs[0][wave * 32 + 16][0]);

  int cur = 0;
#pragma unroll 2
  for (int kk = 0; kk < K; kk += 32, cur ^= 1) {
    __syncthreads();
    if (kk + 32 < K) {
      gl16(Aw0 + kk + 32, &As[cur ^ 1][wave * 32][0]);
      gl16(Aw1 + kk + 32, &As[cur ^ 1][wave * 32 + 16][0]);
      gl16(Bw0 + kk + 32, &Bs[cur ^ 1][wave * 32][0]);
      gl16(Bw1 + kk + 32, &Bs[cur ^ 1][wave * 32 + 16][0]);
    }
    bf16x8 af[4], bfv[NJ];
#pragma unroll
    for (int i = 0; i < 4; i++)
      af[i] = *reinterpret_cast<const bf16x8*>(&As[cur][wm + i * 16 + l15][sq]);
#pragma unroll
    for (int j = 0; j < NJ; j++)
      bfv[j] = *reinterpret_cast<const bf16x8*>(&Bs[cur][wn + j * 16 + l15][sq]);
#pragma unroll
    for (int i = 0; i < 4; i++)
#pragma unroll
      for (int j = 0; j < NJ; j++)
        acc[i][j] = __builtin_amdgcn_mfma_f32_16x16x32_bf16(af[i], bfv[j], acc[i][j], 0, 0, 0);
  }

  if (n0 >= 2048) {
    // ---- V blocks: LDS transpose (LT overlays As/Bs) -> coalesced stores along s ----
    const int b = m0 >> 11, sbase = m0 & 2047;
#pragma unroll
    for (int p = 0; p < 2; p++) {
      __syncthreads();
      if ((wave & 1) == p) {
#pragma unroll
        for (int j = 0; j < NJ; j++) {
          const int n = n0 + wn + j * 16 + l15;
          const float vb = bias[n];
#pragma unroll
          for (int i = 0; i < 4; i++) {
            uint2 pw;
            pw.x = pk2(acc[i][j][0] + vb, acc[i][j][1] + vb);
            pw.y = pk2(acc[i][j][2] + vb, acc[i][j][3] + vb);
            *reinterpret_cast<uint2*>(&LT[j * 16 + l15][wm + i * 16 + quad * 4]) = pw;
          }
        }
      }
      __syncthreads();
      const int h = ((n0 - 2048) >> 6) + p;
      const int bh = b * 16 + h;
      const int nl = tid >> 2, cc = (tid & 3) * 32;
      u16* dst = &Vt[((size_t)bh * 64 + nl) * S + sbase + cc];
#pragma unroll
      for (int k = 0; k < 4; k++)
        reinterpret_cast<uint4*>(dst)[k] = *reinterpret_cast<const uint4*>(&LT[nl][cc + k * 8]);
    }
  } else {
    // ---- Q/K blocks: direct stores (coalesced over l15) ----
#pragma unroll
    for (int i = 0; i < 4; i++) {
#pragma unroll
      for (int j = 0; j < NJ; j++) {
#pragma unroll
        for (int r = 0; r < 4; r++) {
          const int m = m0 + wm + i * 16 + quad * 4 + r;
          const int n = n0 + wn + j * 16 + l15;
          const float v = acc[i][j][r] + bias[n];
          const int h = (n >> 6) & 15, dh = n & 63;
          const int b = m >> 11, s = m & 2047;
          const int bh = b * 16 + h;
          if (n < 1024) Qb[((size_t)bh * S + s) * 64 + dh] = f2bfr(v * SCQ);
          else          Kb[((size_t)bh * S + s) * 64 + dh] = f2bfr(v);
        }
      }
    }
  }
}

// ---- out-proj GEMM: 128x64 tile, BK=64 (R4-proven shape: best of the three
// gemm2 variants tried; split-K's 80MB partial round-trip cost +14us, 64x64
// was +3us vs this). Grid 512 = 2 blocks/CU; BK=64 buys latency tolerance
// (16 steps, 16 MFMA + 12 b128 per step). + bijective XCD swizzle (512=8*64).
// Swizzle: 128B rows = 8 slots; logical slot l stored at physical l^(row&7).
__global__ __launch_bounds__(256, 2) void k_gemm2(const u16* __restrict__ A, const u16* __restrict__ Bt,
                                                  const float* __restrict__ bias, float* __restrict__ outF) {
  constexpr int K = 1024, N = 1024;
  constexpr int ASZ = 2 * 128 * 64 * 2;  // 32768
  __shared__ __align__(16) char smem[ASZ + 2 * 64 * 64 * 2];  // 49152
  auto As = reinterpret_cast<u16(*)[128][64]>(smem);
  auto Bs = reinterpret_cast<u16(*)[64][64]>(smem + ASZ);
  const int tid = threadIdx.x;
  const int lane = tid & 63, wave = tid >> 6;
  const int l15 = lane & 15, quad = lane >> 4;
  // XCD swizzle: nwg = 16*32 = 512, chunk = 64
  const int bid0 = blockIdx.x + 16 * blockIdx.y;
  const int bid = (bid0 & 7) * 64 + (bid0 >> 3);
  const int m0 = (bid >> 4) * 128, n0 = (bid & 15) * 64;
  const int wm = (wave >> 1) * 64, wn = (wave & 1) * 32;
  const int srow = lane >> 3;                       // 0..7 row within 8-row chunk
  const int scol = ((lane & 7) ^ srow) * 8;         // inverse-swizzled source col

  f32x4 acc[4][2];
#pragma unroll
  for (int i = 0; i < 4; i++)
#pragma unroll
    for (int j = 0; j < 2; j++) acc[i][j] = (f32x4){0.f, 0.f, 0.f, 0.f};

  // staging pointers: A 16 chunks of 8 rows (4/wave), B 8 chunks (2/wave)
  const u16* Ap[4];
  const u16* Bp[2];
#pragma unroll
  for (int c = 0; c < 4; c++)
    Ap[c] = &A[(size_t)(m0 + (wave * 4 + c) * 8 + srow) * K + scol];
#pragma unroll
  for (int c = 0; c < 2; c++)
    Bp[c] = &Bt[(size_t)(n0 + (wave * 2 + c) * 8 + srow) * K + scol];

  // prologue: stage K-tile 0 into buf 0
#pragma unroll
  for (int c = 0; c < 4; c++) gl16(Ap[c], &As[0][(wave * 4 + c) * 8][0]);
#pragma unroll
  for (int c = 0; c < 2; c++) gl16(Bp[c], &Bs[0][(wave * 2 + c) * 8][0]);

  int cur = 0;
#pragma unroll 2
  for (int kk = 0; kk < K; kk += 64, cur ^= 1) {
    __syncthreads();  // buf[cur] staged; prev reads of buf[cur^1] done
    if (kk + 64 < K) {
#pragma unroll
      for (int c = 0; c < 4; c++) gl16(Ap[c] + kk + 64, &As[cur ^ 1][(wave * 4 + c) * 8][0]);
#pragma unroll
      for (int c = 0; c < 2; c++) gl16(Bp[c] + kk + 64, &Bs[cur ^ 1][(wave * 2 + c) * 8][0]);
    }
#pragma unroll
    for (int ks = 0; ks < 2; ks++) {
      const int sc = ((ks * 4 + quad) ^ (l15 & 7)) * 8;  // swizzled read col
      bf16x8 af[4], bfv[2];
#pragma unroll
      for (int i = 0; i < 4; i++)
        af[i] = *reinterpret_cast<const bf16x8*>(&As[cur][wm + i * 16 + l15][sc]);
#pragma unroll
      for (int j = 0; j < 2; j++)
        bfv[j] = *reinterpret_cast<const bf16x8*>(&Bs[cur][wn + j * 16 + l15][sc]);
#pragma unroll
      for (int i = 0; i < 4; i++)
#pragma unroll
        for (int j = 0; j < 2; j++)
          acc[i][j] = __builtin_amdgcn_mfma_f32_16x16x32_bf16(af[i], bfv[j], acc[i][j], 0, 0, 0);
    }
  }

#pragma unroll
  for (int i = 0; i < 4; i++)
#pragma unroll
    for (int j = 0; j < 2; j++)
#pragma unroll
      for (int r = 0; r < 4; r++) {
        const int m = m0 + wm + i * 16 + quad * 4 + r;
        const int n = n0 + wn + j * 16 + l15;
        outF[(size_t)m * N + n] = acc[i][j][r] + bias[n];
      }
}

// ---- flash attention, 32x32x16 MFMA, fixed-max softmax (scores bounded) ----
// block = 128 q (4 waves x 32 q), KVBLK=64. XCD swizzle (FETCH 69.7->12.3MB).
// T5 setprio. T12: P fragments built IN-REGISTER via pk2 + v_permlane32_swap
// (verified R9: attn 54.3->49.7, bank-conflict 2.2M->98K).
__global__ __launch_bounds__(256, 2) void k_attn(const u16* __restrict__ Qb,
                                                 const u16* __restrict__ Kb,
                                                 const u16* __restrict__ Vt,
                                                 u16* __restrict__ attnB) {
  __shared__ u16 Ks[64][72];     // [key][dh]
  __shared__ u16 Vs[64][72];     // [dh][key_local]
  __shared__ u16 Pl[4][32][72];  // epilogue-only (O staging)
  const int tid = threadIdx.x;
  const int lane = tid & 63, wave = tid >> 6;
  const int l31 = lane & 31, hi = lane >> 5;
  // XCD swizzle: nwg = 512, chunk = 64 (4 bh of 16 q-blocks per XCD)
  const int bid0 = blockIdx.x + 16 * blockIdx.y;
  const int bid = (bid0 & 7) * 64 + (bid0 >> 3);
  const int bh = bid >> 4;
  const int q0 = (bid & 15) * 128;
  const u16* Qh = Qb + (size_t)bh * S * 64;
  const u16* Kh = Kb + (size_t)bh * S * 64;
  const u16* Vh = Vt + (size_t)bh * 64 * S;
  const int qrow = q0 + wave * 32 + l31;
  bf16x8 qf[4];  // Q (pre-scaled by SCQ) as B-operand: n = lane&31 = q
#pragma unroll
  for (int f = 0; f < 4; f++)
    qf[f] = *reinterpret_cast<const bf16x8*>(&Qh[(size_t)qrow * 64 + f * 16 + hi * 8]);

  const int r0 = tid >> 3, c0 = (tid & 7) * 8;  // staging: 8 lanes x 16B per 128B row

  float li = 0.f;
  f32x16 o0, o1;  // O d-tiles: d = dt*32 + (reg&3)+8*(reg>>2)+4*hi
#pragma unroll
  for (int r = 0; r < 16; r++) { o0[r] = 0.f; o1[r] = 0.f; }

  uint4 pk0 = *reinterpret_cast<const uint4*>(&Kh[(size_t)r0 * 64 + c0]);
  uint4 pk1 = *reinterpret_cast<const uint4*>(&Kh[(size_t)(r0 + 32) * 64 + c0]);
  uint4 pv0 = *reinterpret_cast<const uint4*>(&Vh[(size_t)r0 * S + c0]);
  uint4 pv1 = *reinterpret_cast<const uint4*>(&Vh[(size_t)(r0 + 32) * S + c0]);

  for (int kb = 0; kb < S / 64; kb++) {
    __syncthreads();  // prev tile consumed
    *reinterpret_cast<uint4*>(&Ks[r0][c0]) = pk0;
    *reinterpret_cast<uint4*>(&Ks[r0 + 32][c0]) = pk1;
    *reinterpret_cast<uint4*>(&Vs[r0][c0]) = pv0;
    *reinterpret_cast<uint4*>(&Vs[r0 + 32][c0]) = pv1;
    __syncthreads();  // tile ready
    if (kb + 1 < S / 64) {
      const u16* Kn = Kh + (size_t)(kb + 1) * 64 * 64;
      pk0 = *reinterpret_cast<const uint4*>(&Kn[(size_t)r0 * 64 + c0]);
      pk1 = *reinterpret_cast<const uint4*>(&Kn[(size_t)(r0 + 32) * 64 + c0]);
      pv0 = *reinterpret_cast<const uint4*>(&Vh[(size_t)r0 * S + (kb + 1) * 64 + c0]);
      pv1 = *reinterpret_cast<const uint4*>(&Vh[(size_t)(r0 + 32) * S + (kb + 1) * 64 + c0]);
    }
    // QK^T: 2 key-tiles x 4 k-steps (Q pre-scaled -> z is log2-domain score)
    f32x16 z[2];
    __builtin_amdgcn_s_setprio(1);
#pragma unroll
    for (int kt = 0; kt < 2; kt++) {
#pragma unroll
      for (int r = 0; r < 16; r++) z[kt][r] = 0.f;
#pragma unroll
      for (int f = 0; f < 4; f++) {
        const bf16x8 a = *reinterpret_cast<const bf16x8*>(&Ks[kt * 32 + l31][f * 16 + hi * 8]);
        z[kt] = __builtin_amdgcn_mfma_f32_32x32x16_bf16(a, qf[f], z[kt], 0, 0, 0);
      }
    }
    __builtin_amdgcn_s_setprio(0);
    // p = exp2(z); accumulate denominator (4-way partials)
    float s0 = 0.f, s1 = 0.f, s2 = 0.f, s3 = 0.f;
#pragma unroll
    for (int kt = 0; kt < 2; kt++)
#pragma unroll
      for (int r = 0; r < 16; r++) {
        const float p = __builtin_amdgcn_exp2f(z[kt][r]);
        z[kt][r] = p;
        if ((r & 3) == 0) s0 += p; else if ((r & 3) == 1) s1 += p;
        else if ((r & 3) == 2) s2 += p; else s3 += p;
      }
    li += (s0 + s1) + (s2 + s3);
    // PV: A = V^T rows, B = P built in-register (pk2 + permlane32_swap)
    __builtin_amdgcn_s_setprio(1);
#pragma unroll
    for (int kt = 0; kt < 2; kt++) {
#pragma unroll
      for (int s = 0; s < 2; s++) {
        u32 w0 = pk2(z[kt][s * 8 + 0], z[kt][s * 8 + 1]);
        u32 w2 = pk2(z[kt][s * 8 + 4], z[kt][s * 8 + 5]);
        asm("v_permlane32_swap_b32 %0, %1" : "+v"(w0), "+v"(w2));
        u32 w1 = pk2(z[kt][s * 8 + 2], z[kt][s * 8 + 3]);
        u32 w3 = pk2(z[kt][s * 8 + 6], z[kt][s * 8 + 7]);
        asm("v_permlane32_swap_b32 %0, %1" : "+v"(w1), "+v"(w3));
        uint4 wv;
        wv.x = w0; wv.y = w1; wv.z = w2; wv.w = w3;
        const bf16x8 bp = __builtin_bit_cast(bf16x8, wv);
        const int f = kt * 2 + s;
        const bf16x8 av0 = *reinterpret_cast<const bf16x8*>(&Vs[l31][f * 16 + hi * 8]);
        const bf16x8 av1 = *reinterpret_cast<const bf16x8*>(&Vs[32 + l31][f * 16 + hi * 8]);
        o0 = __builtin_amdgcn_mfma_f32_32x32x16_bf16(av0, bp, o0, 0, 0, 0);
        o1 = __builtin_amdgcn_mfma_f32_32x32x16_bf16(av1, bp, o1, 0, 0, 0);
      }
    }
    __builtin_amdgcn_s_setprio(0);
  }
  li += __shfl_xor(li, 32);
  const float inv = 1.f / li;
  // O -> Pl[q][d] (wave-private), then coalesced store
#pragma unroll
  for (int dt = 0; dt < 2; dt++) {
    const f32x16& od = dt ? o1 : o0;
#pragma unroll
    for (int g = 0; g < 4; g++) {
      uint2 ow;
      ow.x = pk2(od[g * 4 + 0] * inv, od[g * 4 + 1] * inv);
      ow.y = pk2(od[g * 4 + 2] * inv, od[g * 4 + 3] * inv);
      *reinterpret_cast<uint2*>(&Pl[wave][l31][dt * 32 + g * 8 + hi * 4]) = ow;
    }
  }
  const int b = bh >> 4, h = bh & 15;
  const int mbase = b * S + q0 + wave * 32;
  const int qr = lane >> 1, ch = (lane & 1) * 32;
  u16* dst = &attnB[(size_t)(mbase + qr) * D + h * 64 + ch];
#pragma unroll
  for (int c = 0; c < 4; c++)
    reinterpret_cast<uint4*>(dst)[c] = *reinterpret_cast<const uint4*>(&Pl[wave][qr][ch + c * 8]);
}

extern "C" void kernel_launch(void* const* d_in, const int* in_sizes, int n_in,
                              void* d_out, int out_size, void* d_ws, size_t ws_size,
                              hipStream_t stream) {
  const float* x = (const float*)d_in[0];
  const float* Wqkv = (const float*)d_in[1];
  const float* bqkv = (const float*)d_in[2];
  const float* Wout = (const float*)d_in[3];
  const float* bout = (const float*)d_in[4];
  float* out = (float*)d_out;

  char* p = (char*)d_ws;
  u16* WoutT = (u16*)p; p += (size_t)1024 * 1024 * 2;     // 2MB  (live thru gemm2)
  u16* attnB = (u16*)p; p += (size_t)4096 * 1024 * 2;     // 8MB  (live thru gemm2)
  u16* Xb = (u16*)p;    p += (size_t)4096 * 1024 * 2;     // 8MB  (dead after gemm0)
  u16* WqkvT = (u16*)p; p += (size_t)3072 * 1024 * 2;     // 6MB  (dead after gemm0)
  u16* Vt = (u16*)p;    p += (size_t)32 * 64 * 2048 * 2;  // 8MB  (dead after attn)
  u16* Qb = (u16*)p;    p += (size_t)32 * 2048 * 64 * 2;  // 8MB  (dead after attn)
  u16* Kb = (u16*)p;    p += (size_t)32 * 2048 * 64 * 2;  // 8MB  (dead after attn)

  k_prep<<<4096 + 3072 + 1024, 256, 0, stream>>>(x, Xb, Wqkv, WqkvT, Wout, WoutT);
  k_gemm0<<<dim3(3072 / 128, 4096 / 128), 256, 0, stream>>>(
      Xb, WqkvT, bqkv, 4096, 3072, 1024, Qb, Kb, Vt);
  k_attn<<<dim3(2048 / 128, 32), 256, 0, stream>>>(Qb, Kb, Vt, attnB);
  k_gemm2<<<dim3(1024 / 64, 4096 / 128), 256, 0, stream>>>(attnB, WoutT, bout, out);
}